// Round 1
// baseline (222.908 us; speedup 1.0000x reference)
//
#include <hip/hip_runtime.h>

// Derivative1D: y[b, i, c] = x[b, i+1, c] - x[b, i, c]
// x: (B=64, L=16384, C=32) fp32 contiguous; y: (B, L-1, C) fp32.
// Flattened per batch: out[r] = x[r + C] - x[r], r in [0, (L-1)*C).
// Pure streaming kernel -> float4 loads/stores, 2D grid (no int division).

constexpr int B = 64;
constexpr int L = 16384;
constexpr int C = 32;
constexpr int PER_BATCH = (L - 1) * C;        // 524256 floats per batch (out)
constexpr int PER_BATCH_V4 = PER_BATCH / 4;   // 131064 float4 per batch
constexpr int IN_PER_BATCH = L * C;           // 524288 floats per batch (in)

__global__ __launch_bounds__(256) void deriv1d_kernel(const float* __restrict__ x,
                                                      float* __restrict__ out) {
    int r4 = blockIdx.x * 256 + threadIdx.x;   // float4 index within batch
    if (r4 >= PER_BATCH_V4) return;
    int b = blockIdx.y;

    size_t in_base  = (size_t)b * IN_PER_BATCH + (size_t)r4 * 4;
    size_t out_base = (size_t)b * PER_BATCH    + (size_t)r4 * 4;

    const float4 a  = *reinterpret_cast<const float4*>(x + in_base);
    const float4 n  = *reinterpret_cast<const float4*>(x + in_base + C);

    float4 d;
    d.x = n.x - a.x;
    d.y = n.y - a.y;
    d.z = n.z - a.z;
    d.w = n.w - a.w;

    *reinterpret_cast<float4*>(out + out_base) = d;
}

extern "C" void kernel_launch(void* const* d_in, const int* in_sizes, int n_in,
                              void* d_out, int out_size, void* d_ws, size_t ws_size,
                              hipStream_t stream) {
    const float* x = (const float*)d_in[0];
    float* out = (float*)d_out;

    // 131064 float4 per batch -> 512 blocks of 256 (131072 threads, tail masked)
    dim3 grid((PER_BATCH_V4 + 255) / 256, B);
    dim3 block(256);
    deriv1d_kernel<<<grid, block, 0, stream>>>(x, out);
}